// Round 3
// baseline (2101.435 us; speedup 1.0000x reference)
//
#include <hip/hip_runtime.h>
#include <cmath>

typedef unsigned short u16;
typedef unsigned short u16x2 __attribute__((ext_vector_type(2)));
typedef unsigned short u16x8 __attribute__((ext_vector_type(8)));
typedef short s16x8 __attribute__((ext_vector_type(8)));
typedef float f32x4 __attribute__((ext_vector_type(4)));
typedef float f32x2 __attribute__((ext_vector_type(2)));

#define B_SZ 16
#define HW 56
#define L_TOK 3136      // 56*56
#define C_DIM 512
#define NHEAD 16
#define DHEAD 32
#define WS7 7
#define NWIN 49
#define ROWS_TOTAL 50176   // 16*3136
#define MLP_DIM 2048
#define CHUNK_B 2
#define CHUNK_ROWS 6272    // CHUNK_B*3136
#define N_CHUNKS 8

__device__ __forceinline__ float bf2f(u16 u) {
    union { unsigned int i; float f; } z;
    z.i = ((unsigned int)u) << 16;
    return z.f;
}
__device__ __forceinline__ u16 f2bf(float f) {
    union { float f; unsigned int i; } z;
    z.f = f;
    unsigned int r = z.i + 0x7fffu + ((z.i >> 16) & 1u);
    return (u16)(r >> 16);
}

// ---------------------------------------------------------------------------
// 1) mod = silu(emb) @ adaLN_w + adaLN_b   -> fp32 [16, 3072]  (all fp32 in)
// ---------------------------------------------------------------------------
__global__ __launch_bounds__(256)
void mod_kernel(const float* __restrict__ emb, const float* __restrict__ w,
                const float* __restrict__ bias, float* __restrict__ mod)
{
    int b = blockIdx.x;
    __shared__ float se[512];
    int t = threadIdx.x;
    for (int i = t; i < 512; i += 256) {
        float e = emb[b * 512 + i];
        se[i] = e / (1.0f + expf(-e));
    }
    __syncthreads();
    for (int o = t; o < 3072; o += 256) {
        float acc = bias[o];
        for (int k = 0; k < 512; ++k)
            acc += se[k] * w[(size_t)k * 3072 + o];
        mod[b * 3072 + o] = acc;
    }
}

// ---------------------------------------------------------------------------
// 2) weight transpose + bf16 cast: Wt[n][k] = bf16(W[k][n])
// ---------------------------------------------------------------------------
__global__ __launch_bounds__(1024)
void transpose_kernel(const float* __restrict__ W, u16* __restrict__ Wt, int K, int N)
{
    __shared__ float tile[32][33];
    int k0 = blockIdx.x * 32, n0 = blockIdx.y * 32;
    tile[threadIdx.y][threadIdx.x] = W[(size_t)(k0 + threadIdx.y) * N + (n0 + threadIdx.x)];
    __syncthreads();
    Wt[(size_t)(n0 + threadIdx.y) * K + (k0 + threadIdx.x)] = f2bf(tile[threadIdx.x][threadIdx.y]);
}

// ---------------------------------------------------------------------------
// 3) LN + adaLN modulate; fp32 in, bf16 out.
//    WINDOWED=1: read global seq row (rowBase+blk), write chunk-local
//                window layout [(b_local*64+wi)*49+n][512]
//    WINDOWED=0: write chunk-local seq row
// ---------------------------------------------------------------------------
template<int WINDOWED>
__global__ __launch_bounds__(256)
void ln_kernel(const float* __restrict__ xin, const float* __restrict__ mod,
               u16* __restrict__ out, int shOff, int scOff, int rowBase)
{
    int rbl = blockIdx.x;                 // chunk-local row
    int rb = rbl + rowBase;               // global sequence row
    int b = rb / L_TOK, l = rb - b * L_TOK;
    const float* xr = xin + (size_t)rb * C_DIM;
    int t = threadIdx.x;
    int c0 = t * 2;
    f32x2 u = *(const f32x2*)(xr + c0);
    float v0 = u.x, v1 = u.y;
    float s = v0 + v1, q = v0 * v0 + v1 * v1;
    #pragma unroll
    for (int off = 32; off > 0; off >>= 1) {
        s += __shfl_down(s, off);
        q += __shfl_down(q, off);
    }
    __shared__ float ss[4], qq[4];
    int wv = t >> 6;
    if ((t & 63) == 0) { ss[wv] = s; qq[wv] = q; }
    __syncthreads();
    float S = ss[0] + ss[1] + ss[2] + ss[3];
    float Q = qq[0] + qq[1] + qq[2] + qq[3];
    float mu = S * (1.0f / 512.0f);
    float var = Q * (1.0f / 512.0f) - mu * mu;
    float rstd = rsqrtf(var + 1e-6f);
    const float* mb = mod + b * 3072;
    float y0 = (v0 - mu) * rstd * (1.0f + mb[scOff + c0]) + mb[shOff + c0];
    float y1 = (v1 - mu) * rstd * (1.0f + mb[scOff + c0 + 1]) + mb[shOff + c0 + 1];
    size_t drow;
    if (WINDOWED) {
        int hh = l / HW, ww = l - hh * HW;
        int hs = hh - 3; if (hs < 0) hs += HW;
        int ws2 = ww - 3; if (ws2 < 0) ws2 += HW;
        int wi = (hs / WS7) * 8 + (ws2 / WS7);
        int n  = (hs % WS7) * WS7 + (ws2 % WS7);
        int b_local = rbl / L_TOK;
        drow = (size_t)((b_local * 64 + wi) * NWIN + n);
    } else {
        drow = (size_t)rbl;
    }
    u16x2 o; o.x = f2bf(y0); o.y = f2bf(y1);
    *(u16x2*)(out + drow * C_DIM + c0) = o;
}

// ---------------------------------------------------------------------------
// 4) GEMM: C[M,N] = A[M,K] @ Bt[N,K]^T + bias (bias fp32)
//    128x128 tile, BK=32, 4 waves each 64x64 via 4x4 mfma_f32_16x16x32_bf16
//    EPI 0: bias -> bf16 out (qkv) | EPI 1: bias+GELU -> bf16 out (ff1)
//    EPI 2: bias, window-reverse+unshift, x + g_sa*v -> fp32 out (proj)
//    EPI 3: bias, x2 + g_ff*v -> fp32 out (ff2)
// ---------------------------------------------------------------------------
template<int EPI>
__global__ __launch_bounds__(256)
void gemm128(const u16* __restrict__ A, const u16* __restrict__ Bt,
             const float* __restrict__ bias, void* __restrict__ outv,
             const float* __restrict__ resid, const float* __restrict__ mod,
             int N, int K, int rowOffset)
{
    __shared__ u16 sA[128][40];   // +8 pad: rows 16B aligned, 2-way bank alias free
    __shared__ u16 sB[128][40];
    const int tid  = threadIdx.x;
    const int lane = tid & 63;
    const int wave = tid >> 6;
    const int wr = (wave >> 1) * 64;
    const int wc = (wave & 1) * 64;
    const int quad = lane >> 4;
    const int mrow = lane & 15;
    const int rowBase = blockIdx.x * 128;
    const int colBase = blockIdx.y * 128;

    const int ar = tid >> 1;
    const int ac = (tid & 1) * 16;
    const u16* Ap = A  + (size_t)(rowBase + ar) * K + ac;
    const u16* Bp = Bt + (size_t)(colBase + ar) * K + ac;

    f32x4 acc[4][4] = {};

    for (int kk = 0; kk < K; kk += 32) {
        u16x8 a0 = *(const u16x8*)(Ap + kk);
        u16x8 a1 = *(const u16x8*)(Ap + kk + 8);
        u16x8 b0 = *(const u16x8*)(Bp + kk);
        u16x8 b1 = *(const u16x8*)(Bp + kk + 8);
        __syncthreads();
        *(u16x8*)&sA[ar][ac]     = a0;
        *(u16x8*)&sA[ar][ac + 8] = a1;
        *(u16x8*)&sB[ar][ac]     = b0;
        *(u16x8*)&sB[ar][ac + 8] = b1;
        __syncthreads();
        s16x8 af[4], bg[4];
        #pragma unroll
        for (int tt = 0; tt < 4; ++tt) {
            af[tt] = *(const s16x8*)&sA[wr + tt * 16 + mrow][quad * 8];
            bg[tt] = *(const s16x8*)&sB[wc + tt * 16 + mrow][quad * 8];
        }
        #pragma unroll
        for (int tm = 0; tm < 4; ++tm)
            #pragma unroll
            for (int tn = 0; tn < 4; ++tn)
                acc[tm][tn] = __builtin_amdgcn_mfma_f32_16x16x32_bf16(
                    af[tm], bg[tn], acc[tm][tn], 0, 0, 0);
    }

    #pragma unroll
    for (int tm = 0; tm < 4; ++tm) {
        #pragma unroll
        for (int tn = 0; tn < 4; ++tn) {
            int col = colBase + wc + tn * 16 + mrow;
            float bv = bias[col];
            #pragma unroll
            for (int i = 0; i < 4; ++i) {
                int r = rowBase + wr + tm * 16 + quad * 4 + i;   // chunk-local
                float v = acc[tm][tn][i] + bv;
                if constexpr (EPI == 0) {
                    ((u16*)outv)[(size_t)r * N + col] = f2bf(v);
                } else if constexpr (EPI == 1) {
                    float g = 0.5f * v * (1.0f + erff(v * 0.70710678118654752f));
                    ((u16*)outv)[(size_t)r * N + col] = f2bf(g);
                } else if constexpr (EPI == 2) {
                    int rg = r + rowOffset;        // global window-layout row
                    int b = rg / L_TOK;
                    int rem = rg - b * L_TOK;
                    int wi = rem / NWIN;
                    int n  = rem - wi * NWIN;
                    int hs  = (wi >> 3) * WS7 + n / WS7;
                    int ws2 = (wi & 7) * WS7 + n % WS7;
                    int hh = hs + 3;  if (hh >= HW)  hh -= HW;
                    int ww = ws2 + 3; if (ww >= HW)  ww -= HW;
                    size_t dst = ((size_t)(b * L_TOK + hh * HW + ww)) * C_DIM + col;
                    float g = mod[b * 3072 + 1024 + col];
                    ((float*)outv)[dst] = resid[dst] + g * v;
                } else {  // EPI == 3
                    int rg = r + rowOffset;        // global sequence row
                    int b = rg / L_TOK;
                    size_t dst = (size_t)rg * C_DIM + col;
                    float g = mod[b * 3072 + 2560 + col];
                    ((float*)outv)[dst] = resid[dst] + g * v;
                }
            }
        }
    }
}

// ---------------------------------------------------------------------------
// 5) windowed attention, one block per (chunk-local window, head)
//    qkv bf16 in, bias_table fp32, bf16 out
// ---------------------------------------------------------------------------
__global__ __launch_bounds__(256)
void attn_kernel(const u16* __restrict__ qkv, const float* __restrict__ bias_table,
                 u16* __restrict__ out)
{
    int w = blockIdx.x;       // chunk-local: b_local*64 + wi
    int h = blockIdx.y;       // 0..15
    int wi = w & 63;
    __shared__ float sq[NWIN][DHEAD];
    __shared__ float sk[NWIN][DHEAD];
    __shared__ float sv[NWIN][DHEAD];
    __shared__ float sS[NWIN][NWIN + 1];
    int t = threadIdx.x;
    const float scale = 0.17677669529663687f;   // 1/sqrt(32)

    for (int e = t; e < NWIN * DHEAD; e += 256) {
        int n = e >> 5, d = e & 31;
        size_t base = ((size_t)(w * NWIN + n)) * 1536 + h * DHEAD + d;
        sq[n][d] = bf2f(qkv[base]) * scale;
        sk[n][d] = bf2f(qkv[base + 512]);
        sv[n][d] = bf2f(qkv[base + 1024]);
    }
    __syncthreads();

    int wh = wi >> 3, ww = wi & 7;
    for (int e = t; e < NWIN * NWIN; e += 256) {
        int n = e / NWIN, m = e - n * NWIN;
        float s = 0.0f;
        #pragma unroll
        for (int d = 0; d < DHEAD; ++d) s += sq[n][d] * sk[m][d];
        int nh_ = n / WS7, nw_ = n % WS7;
        int mh_ = m / WS7, mw_ = m % WS7;
        int idx = (nh_ - mh_ + 6) * 13 + (nw_ - mw_ + 6);
        s += bias_table[idx * NHEAD + h];
        // shift-mask regions on the shifted grid; bands at 49 and 53
        int gnh = wh * WS7 + nh_, gnw = ww * WS7 + nw_;
        int gmh = wh * WS7 + mh_, gmw = ww * WS7 + mw_;
        int rn = (gnh < 49 ? 0 : (gnh < 53 ? 1 : 2)) * 3 + (gnw < 49 ? 0 : (gnw < 53 ? 1 : 2));
        int rm = (gmh < 49 ? 0 : (gmh < 53 ? 1 : 2)) * 3 + (gmw < 49 ? 0 : (gmw < 53 ? 1 : 2));
        if (rn != rm) s -= 100.0f;
        sS[n][m] = s;
    }
    __syncthreads();

    if (t < NWIN) {
        float mx = -1e30f;
        for (int m = 0; m < NWIN; ++m) mx = fmaxf(mx, sS[t][m]);
        float sum = 0.0f;
        for (int m = 0; m < NWIN; ++m) { float p = expf(sS[t][m] - mx); sS[t][m] = p; sum += p; }
        float inv = 1.0f / sum;
        for (int m = 0; m < NWIN; ++m) sS[t][m] *= inv;
    }
    __syncthreads();

    for (int e = t; e < NWIN * DHEAD; e += 256) {
        int n = e >> 5, d = e & 31;
        float o = 0.0f;
        for (int m = 0; m < NWIN; ++m) o += sS[n][m] * sv[m][d];
        out[((size_t)(w * NWIN + n)) * C_DIM + h * DHEAD + d] = f2bf(o);
    }
}

// ---------------------------------------------------------------------------
// fp32 I/O, bf16 compute core. x2 lives in d_out (fp32, fully overwritten
// each call; ff2 epilogue reads-then-writes elementwise by owning thread).
// Workspace peak 70.7 MB.
// ---------------------------------------------------------------------------
extern "C" void kernel_launch(void* const* d_in, const int* in_sizes, int n_in,
                              void* d_out, int out_size, void* d_ws, size_t ws_size,
                              hipStream_t stream)
{
    const float* x       = (const float*)d_in[0];
    const float* emb     = (const float*)d_in[1];
    const float* adaLN_w = (const float*)d_in[2];
    const float* adaLN_b = (const float*)d_in[3];
    const float* qkv_w   = (const float*)d_in[4];
    const float* qkv_b   = (const float*)d_in[5];
    const float* proj_w  = (const float*)d_in[6];
    const float* proj_b  = (const float*)d_in[7];
    const float* relb    = (const float*)d_in[8];
    const float* ff_w1   = (const float*)d_in[9];
    const float* ff_b1   = (const float*)d_in[10];
    const float* ff_w2   = (const float*)d_in[11];
    const float* ff_b2   = (const float*)d_in[12];
    float* outp = (float*)d_out;

    char* ws = (char*)d_ws;
    float* mod   = (float*)(ws + 0);                  //    196,608 B
    u16* wT_qkv  = (u16*)(ws + 196608);               //  1,572,864 B
    u16* wT_proj = (u16*)(ws + 1769472);              //    524,288 B
    u16* wT_ff1  = (u16*)(ws + 2293760);              //  2,097,152 B
    u16* wT_ff2  = (u16*)(ws + 4390912);              //  2,097,152 B
    u16* winC    = (u16*)(ws + 6488064);              //  6,422,528 B [6272,512]
    u16* aoC     = (u16*)(ws + 12910592);             //  6,422,528 B [6272,512]
    u16* h2C     = (u16*)(ws + 19333120);             //  6,422,528 B [6272,512]
    u16* qkvC    = (u16*)(ws + 25755648);             // 19,267,584 B [6272,1536]
    u16* ffiC    = (u16*)(ws + 45023232);             // 25,690,112 B [6272,2048]
    // total: 70,713,344 B

    // prolog (once)
    mod_kernel<<<dim3(16), dim3(256), 0, stream>>>(emb, adaLN_w, adaLN_b, mod);
    transpose_kernel<<<dim3(16, 48), dim3(32, 32), 0, stream>>>(qkv_w,  wT_qkv, 512, 1536);
    transpose_kernel<<<dim3(16, 16), dim3(32, 32), 0, stream>>>(proj_w, wT_proj, 512, 512);
    transpose_kernel<<<dim3(16, 64), dim3(32, 32), 0, stream>>>(ff_w1,  wT_ff1, 512, 2048);
    transpose_kernel<<<dim3(64, 16), dim3(32, 32), 0, stream>>>(ff_w2,  wT_ff2, 2048, 512);

    for (int c = 0; c < N_CHUNKS; ++c) {
        int row0 = c * CHUNK_ROWS;
        // LN1 + modulate + shift + window partition: x[row0..] -> winC
        ln_kernel<1><<<dim3(CHUNK_ROWS), dim3(256), 0, stream>>>(
            x, mod, winC, 0, 512, row0);
        // qkv GEMM: winC [6272,512] @ wT_qkv -> qkvC [6272,1536]
        gemm128<0><<<dim3(49, 12), dim3(256), 0, stream>>>(
            winC, wT_qkv, qkv_b, qkvC, nullptr, mod, 1536, 512, 0);
        // attention -> aoC
        attn_kernel<<<dim3(CHUNK_B * 64, 16), dim3(256), 0, stream>>>(qkvC, relb, aoC);
        // proj + window reverse + unshift + residual(x) -> d_out (x2, fp32)
        gemm128<2><<<dim3(49, 4), dim3(256), 0, stream>>>(
            aoC, wT_proj, proj_b, outp, x, mod, 512, 512, row0);
        // LN2 + modulate: d_out[row0..] -> h2C (bf16)
        ln_kernel<0><<<dim3(CHUNK_ROWS), dim3(256), 0, stream>>>(
            outp, mod, h2C, 1536, 2048, row0);
        // FF1 + GELU: h2C -> ffiC
        gemm128<1><<<dim3(49, 16), dim3(256), 0, stream>>>(
            h2C, wT_ff1, ff_b1, ffiC, nullptr, mod, 2048, 512, 0);
        // FF2 + residual(x2) -> d_out
        gemm128<3><<<dim3(49, 4), dim3(256), 0, stream>>>(
            ffiC, wT_ff2, ff_b2, outp, outp, mod, 512, 2048, row0);
    }
}

// Round 4
// 1813.346 us; speedup vs baseline: 1.1589x; 1.1589x over previous
//
#include <hip/hip_runtime.h>
#include <cmath>

typedef unsigned short u16;
typedef unsigned short u16x2 __attribute__((ext_vector_type(2)));
typedef unsigned short u16x8 __attribute__((ext_vector_type(8)));
typedef short s16x8 __attribute__((ext_vector_type(8)));
typedef float f32x4 __attribute__((ext_vector_type(4)));
typedef float f32x2 __attribute__((ext_vector_type(2)));

#define B_SZ 16
#define HW 56
#define L_TOK 3136      // 56*56
#define C_DIM 512
#define NHEAD 16
#define DHEAD 32
#define WS7 7
#define NWIN 49
#define ROWS_TOTAL 50176   // 16*3136
#define MLP_DIM 2048
#define CHUNK_B 2
#define CHUNK_ROWS 6272    // CHUNK_B*3136
#define N_CHUNKS 8

__device__ __forceinline__ float bf2f(u16 u) {
    union { unsigned int i; float f; } z;
    z.i = ((unsigned int)u) << 16;
    return z.f;
}
__device__ __forceinline__ u16 f2bf(float f) {
    union { float f; unsigned int i; } z;
    z.f = f;
    unsigned int r = z.i + 0x7fffu + ((z.i >> 16) & 1u);
    return (u16)(r >> 16);
}

// async global->LDS, 16B per lane; LDS dest = wave-uniform base + lane*16
__device__ __forceinline__ void gl_lds16(const u16* g, u16* l) {
    __builtin_amdgcn_global_load_lds(
        (const __attribute__((address_space(1))) unsigned int*)g,
        (__attribute__((address_space(3))) unsigned int*)l,
        16, 0, 0);
}

// ---------------------------------------------------------------------------
// 1) mod = silu(emb) @ adaLN_w + adaLN_b -> fp32 [16,3072]
//    grid (12,16): block = (o-tile of 256, batch); one output per thread
// ---------------------------------------------------------------------------
__global__ __launch_bounds__(256)
void mod_kernel(const float* __restrict__ emb, const float* __restrict__ w,
                const float* __restrict__ bias, float* __restrict__ mod)
{
    int b = blockIdx.y;
    int o = blockIdx.x * 256 + threadIdx.x;
    __shared__ float se[512];
    for (int i = threadIdx.x; i < 512; i += 256) {
        float e = emb[b * 512 + i];
        se[i] = e / (1.0f + expf(-e));
    }
    __syncthreads();
    float acc = bias[o];
    #pragma unroll 8
    for (int k = 0; k < 512; ++k)
        acc += se[k] * w[(size_t)k * 3072 + o];
    mod[b * 3072 + o] = acc;
}

// ---------------------------------------------------------------------------
// 2) weight transpose + bf16 cast: Wt[n][k] = bf16(W[k][n])
// ---------------------------------------------------------------------------
__global__ __launch_bounds__(1024)
void transpose_kernel(const float* __restrict__ W, u16* __restrict__ Wt, int K, int N)
{
    __shared__ float tile[32][33];
    int k0 = blockIdx.x * 32, n0 = blockIdx.y * 32;
    tile[threadIdx.y][threadIdx.x] = W[(size_t)(k0 + threadIdx.y) * N + (n0 + threadIdx.x)];
    __syncthreads();
    Wt[(size_t)(n0 + threadIdx.y) * K + (k0 + threadIdx.x)] = f2bf(tile[threadIdx.x][threadIdx.y]);
}

// ---------------------------------------------------------------------------
// 3) LN + adaLN modulate; fp32 in, bf16 out.
// ---------------------------------------------------------------------------
template<int WINDOWED>
__global__ __launch_bounds__(256)
void ln_kernel(const float* __restrict__ xin, const float* __restrict__ mod,
               u16* __restrict__ out, int shOff, int scOff, int rowBase)
{
    int rbl = blockIdx.x;                 // chunk-local row
    int rb = rbl + rowBase;               // global sequence row
    int b = rb / L_TOK, l = rb - b * L_TOK;
    const float* xr = xin + (size_t)rb * C_DIM;
    int t = threadIdx.x;
    int c0 = t * 2;
    f32x2 u = *(const f32x2*)(xr + c0);
    float v0 = u.x, v1 = u.y;
    float s = v0 + v1, q = v0 * v0 + v1 * v1;
    #pragma unroll
    for (int off = 32; off > 0; off >>= 1) {
        s += __shfl_down(s, off);
        q += __shfl_down(q, off);
    }
    __shared__ float ss[4], qq[4];
    int wv = t >> 6;
    if ((t & 63) == 0) { ss[wv] = s; qq[wv] = q; }
    __syncthreads();
    float S = ss[0] + ss[1] + ss[2] + ss[3];
    float Q = qq[0] + qq[1] + qq[2] + qq[3];
    float mu = S * (1.0f / 512.0f);
    float var = Q * (1.0f / 512.0f) - mu * mu;
    float rstd = rsqrtf(var + 1e-6f);
    const float* mb = mod + b * 3072;
    float y0 = (v0 - mu) * rstd * (1.0f + mb[scOff + c0]) + mb[shOff + c0];
    float y1 = (v1 - mu) * rstd * (1.0f + mb[scOff + c0 + 1]) + mb[shOff + c0 + 1];
    size_t drow;
    if (WINDOWED) {
        int hh = l / HW, ww = l - hh * HW;
        int hs = hh - 3; if (hs < 0) hs += HW;
        int ws2 = ww - 3; if (ws2 < 0) ws2 += HW;
        int wi = (hs / WS7) * 8 + (ws2 / WS7);
        int n  = (hs % WS7) * WS7 + (ws2 % WS7);
        int b_local = rbl / L_TOK;
        drow = (size_t)((b_local * 64 + wi) * NWIN + n);
    } else {
        drow = (size_t)rbl;
    }
    u16x2 o; o.x = f2bf(y0); o.y = f2bf(y1);
    *(u16x2*)(out + drow * C_DIM + c0) = o;
}

// ---------------------------------------------------------------------------
// 4) GEMM: C[M,N] = A[M,K] @ Bt[N,K]^T + bias
//    128x128 tile, BK=32, 4 waves x (4x4) mfma_f32_16x16x32_bf16.
//    Staging via global_load_lds width=16 (m97 pattern): unpadded LDS tiles,
//    per wave 2 instrs/operand/K-step; wave w owns rows w*32..w*32+31.
//    EPI 0: bias (qkv) | 1: bias+GELU (ff1) | 2: proj epilogue | 3: ff2 epilogue
// ---------------------------------------------------------------------------
template<int EPI>
__global__ __launch_bounds__(256)
void gemm128(const u16* __restrict__ A, const u16* __restrict__ Bt,
             const float* __restrict__ bias, void* __restrict__ outv,
             const float* __restrict__ resid, const float* __restrict__ mod,
             int N, int K, int rowOffset)
{
    __shared__ u16 sA[128][32];   // unpadded: global_load_lds is lane-contiguous
    __shared__ u16 sB[128][32];
    const int tid  = threadIdx.x;
    const int lane = tid & 63;
    const int wave = tid >> 6;
    const int wr = (wave >> 1) * 64;
    const int wc = (wave & 1) * 64;
    const int quad = lane >> 4;
    const int mrow = lane & 15;
    const int rowBase = blockIdx.x * 128;
    const int colBase = blockIdx.y * 128;

    // staging addresses: lane covers (row = r0 + lane/4, 16B chunk = lane%4)
    const int r0   = wave * 32;
    const int lrow = lane >> 2;
    const int lcol = (lane & 3) * 8;          // u16 offset in row
    const u16* gA = A  + (size_t)(rowBase + r0 + lrow) * K + lcol;
    const u16* gB = Bt + (size_t)(colBase + r0 + lrow) * K + lcol;
    u16* lA0 = &sA[r0][0];                    // wave-uniform LDS bases
    u16* lA1 = &sA[r0 + 16][0];
    u16* lB0 = &sB[r0][0];
    u16* lB1 = &sB[r0 + 16][0];
    const size_t gstep = (size_t)16 * K;

    f32x4 acc[4][4] = {};

    for (int kk = 0; kk < K; kk += 32) {
        __syncthreads();                      // prev iter's LDS reads done
        gl_lds16(gA + kk,         lA0);
        gl_lds16(gA + kk + gstep, lA1);
        gl_lds16(gB + kk,         lB0);
        gl_lds16(gB + kk + gstep, lB1);
        __syncthreads();                      // waits vmcnt(0): tile landed
        s16x8 af[4], bg[4];
        #pragma unroll
        for (int tt = 0; tt < 4; ++tt) {
            af[tt] = *(const s16x8*)&sA[wr + tt * 16 + mrow][quad * 8];
            bg[tt] = *(const s16x8*)&sB[wc + tt * 16 + mrow][quad * 8];
        }
        #pragma unroll
        for (int tm = 0; tm < 4; ++tm)
            #pragma unroll
            for (int tn = 0; tn < 4; ++tn)
                acc[tm][tn] = __builtin_amdgcn_mfma_f32_16x16x32_bf16(
                    af[tm], bg[tn], acc[tm][tn], 0, 0, 0);
    }

    #pragma unroll
    for (int tm = 0; tm < 4; ++tm) {
        #pragma unroll
        for (int tn = 0; tn < 4; ++tn) {
            int col = colBase + wc + tn * 16 + mrow;
            float bv = bias[col];
            #pragma unroll
            for (int i = 0; i < 4; ++i) {
                int r = rowBase + wr + tm * 16 + quad * 4 + i;   // chunk-local
                float v = acc[tm][tn][i] + bv;
                if constexpr (EPI == 0) {
                    ((u16*)outv)[(size_t)r * N + col] = f2bf(v);
                } else if constexpr (EPI == 1) {
                    float g = 0.5f * v * (1.0f + erff(v * 0.70710678118654752f));
                    ((u16*)outv)[(size_t)r * N + col] = f2bf(g);
                } else if constexpr (EPI == 2) {
                    int rg = r + rowOffset;        // global window-layout row
                    int b = rg / L_TOK;
                    int rem = rg - b * L_TOK;
                    int wi = rem / NWIN;
                    int n  = rem - wi * NWIN;
                    int hs  = (wi >> 3) * WS7 + n / WS7;
                    int ws2 = (wi & 7) * WS7 + n % WS7;
                    int hh = hs + 3;  if (hh >= HW)  hh -= HW;
                    int ww = ws2 + 3; if (ww >= HW)  ww -= HW;
                    size_t dst = ((size_t)(b * L_TOK + hh * HW + ww)) * C_DIM + col;
                    float g = mod[b * 3072 + 1024 + col];
                    ((float*)outv)[dst] = resid[dst] + g * v;
                } else {  // EPI == 3
                    int rg = r + rowOffset;        // global sequence row
                    int b = rg / L_TOK;
                    size_t dst = (size_t)rg * C_DIM + col;
                    float g = mod[b * 3072 + 2560 + col];
                    ((float*)outv)[dst] = resid[dst] + g * v;
                }
            }
        }
    }
}

// ---------------------------------------------------------------------------
// 5) windowed attention, one block per (chunk-local window, head)
// ---------------------------------------------------------------------------
__global__ __launch_bounds__(256)
void attn_kernel(const u16* __restrict__ qkv, const float* __restrict__ bias_table,
                 u16* __restrict__ out)
{
    int w = blockIdx.x;       // chunk-local: b_local*64 + wi
    int h = blockIdx.y;       // 0..15
    int wi = w & 63;
    __shared__ float sq[NWIN][DHEAD];
    __shared__ float sk[NWIN][DHEAD];
    __shared__ float sv[NWIN][DHEAD];
    __shared__ float sS[NWIN][NWIN + 1];
    int t = threadIdx.x;
    const float scale = 0.17677669529663687f;   // 1/sqrt(32)

    for (int e = t; e < NWIN * DHEAD; e += 256) {
        int n = e >> 5, d = e & 31;
        size_t base = ((size_t)(w * NWIN + n)) * 1536 + h * DHEAD + d;
        sq[n][d] = bf2f(qkv[base]) * scale;
        sk[n][d] = bf2f(qkv[base + 512]);
        sv[n][d] = bf2f(qkv[base + 1024]);
    }
    __syncthreads();

    int wh = wi >> 3, ww = wi & 7;
    for (int e = t; e < NWIN * NWIN; e += 256) {
        int n = e / NWIN, m = e - n * NWIN;
        float s = 0.0f;
        #pragma unroll
        for (int d = 0; d < DHEAD; ++d) s += sq[n][d] * sk[m][d];
        int nh_ = n / WS7, nw_ = n % WS7;
        int mh_ = m / WS7, mw_ = m % WS7;
        int idx = (nh_ - mh_ + 6) * 13 + (nw_ - mw_ + 6);
        s += bias_table[idx * NHEAD + h];
        // shift-mask regions on the shifted grid; bands at 49 and 53
        int gnh = wh * WS7 + nh_, gnw = ww * WS7 + nw_;
        int gmh = wh * WS7 + mh_, gmw = ww * WS7 + mw_;
        int rn = (gnh < 49 ? 0 : (gnh < 53 ? 1 : 2)) * 3 + (gnw < 49 ? 0 : (gnw < 53 ? 1 : 2));
        int rm = (gmh < 49 ? 0 : (gmh < 53 ? 1 : 2)) * 3 + (gmw < 49 ? 0 : (gmw < 53 ? 1 : 2));
        if (rn != rm) s -= 100.0f;
        sS[n][m] = s;
    }
    __syncthreads();

    if (t < NWIN) {
        float mx = -1e30f;
        for (int m = 0; m < NWIN; ++m) mx = fmaxf(mx, sS[t][m]);
        float sum = 0.0f;
        for (int m = 0; m < NWIN; ++m) { float p = expf(sS[t][m] - mx); sS[t][m] = p; sum += p; }
        float inv = 1.0f / sum;
        for (int m = 0; m < NWIN; ++m) sS[t][m] *= inv;
    }
    __syncthreads();

    for (int e = t; e < NWIN * DHEAD; e += 256) {
        int n = e >> 5, d = e & 31;
        float o = 0.0f;
        for (int m = 0; m < NWIN; ++m) o += sS[n][m] * sv[m][d];
        out[((size_t)(w * NWIN + n)) * C_DIM + h * DHEAD + d] = f2bf(o);
    }
}

// ---------------------------------------------------------------------------
// fp32 I/O, bf16 compute core. x2 lives in d_out (fp32, fully overwritten
// each call). Workspace peak 70.7 MB.
// ---------------------------------------------------------------------------
extern "C" void kernel_launch(void* const* d_in, const int* in_sizes, int n_in,
                              void* d_out, int out_size, void* d_ws, size_t ws_size,
                              hipStream_t stream)
{
    const float* x       = (const float*)d_in[0];
    const float* emb     = (const float*)d_in[1];
    const float* adaLN_w = (const float*)d_in[2];
    const float* adaLN_b = (const float*)d_in[3];
    const float* qkv_w   = (const float*)d_in[4];
    const float* qkv_b   = (const float*)d_in[5];
    const float* proj_w  = (const float*)d_in[6];
    const float* proj_b  = (const float*)d_in[7];
    const float* relb    = (const float*)d_in[8];
    const float* ff_w1   = (const float*)d_in[9];
    const float* ff_b1   = (const float*)d_in[10];
    const float* ff_w2   = (const float*)d_in[11];
    const float* ff_b2   = (const float*)d_in[12];
    float* outp = (float*)d_out;

    char* ws = (char*)d_ws;
    float* mod   = (float*)(ws + 0);                  //    196,608 B
    u16* wT_qkv  = (u16*)(ws + 196608);               //  1,572,864 B
    u16* wT_proj = (u16*)(ws + 1769472);              //    524,288 B
    u16* wT_ff1  = (u16*)(ws + 2293760);              //  2,097,152 B
    u16* wT_ff2  = (u16*)(ws + 4390912);              //  2,097,152 B
    u16* winC    = (u16*)(ws + 6488064);              //  6,422,528 B [6272,512]
    u16* aoC     = (u16*)(ws + 12910592);             //  6,422,528 B [6272,512]
    u16* h2C     = (u16*)(ws + 19333120);             //  6,422,528 B [6272,512]
    u16* qkvC    = (u16*)(ws + 25755648);             // 19,267,584 B [6272,1536]
    u16* ffiC    = (u16*)(ws + 45023232);             // 25,690,112 B [6272,2048]
    // total: 70,713,344 B

    // prolog (once)
    mod_kernel<<<dim3(12, 16), dim3(256), 0, stream>>>(emb, adaLN_w, adaLN_b, mod);
    transpose_kernel<<<dim3(16, 48), dim3(32, 32), 0, stream>>>(qkv_w,  wT_qkv, 512, 1536);
    transpose_kernel<<<dim3(16, 16), dim3(32, 32), 0, stream>>>(proj_w, wT_proj, 512, 512);
    transpose_kernel<<<dim3(16, 64), dim3(32, 32), 0, stream>>>(ff_w1,  wT_ff1, 512, 2048);
    transpose_kernel<<<dim3(64, 16), dim3(32, 32), 0, stream>>>(ff_w2,  wT_ff2, 2048, 512);

    for (int c = 0; c < N_CHUNKS; ++c) {
        int row0 = c * CHUNK_ROWS;
        // LN1 + modulate + shift + window partition: x[row0..] -> winC
        ln_kernel<1><<<dim3(CHUNK_ROWS), dim3(256), 0, stream>>>(
            x, mod, winC, 0, 512, row0);
        // qkv GEMM: winC [6272,512] @ wT_qkv -> qkvC [6272,1536]
        gemm128<0><<<dim3(49, 12), dim3(256), 0, stream>>>(
            winC, wT_qkv, qkv_b, qkvC, nullptr, mod, 1536, 512, 0);
        // attention -> aoC
        attn_kernel<<<dim3(CHUNK_B * 64, 16), dim3(256), 0, stream>>>(qkvC, relb, aoC);
        // proj + window reverse + unshift + residual(x) -> d_out (x2, fp32)
        gemm128<2><<<dim3(49, 4), dim3(256), 0, stream>>>(
            aoC, wT_proj, proj_b, outp, x, mod, 512, 512, row0);
        // LN2 + modulate: d_out[row0..] -> h2C (bf16)
        ln_kernel<0><<<dim3(CHUNK_ROWS), dim3(256), 0, stream>>>(
            outp, mod, h2C, 1536, 2048, row0);
        // FF1 + GELU: h2C -> ffiC
        gemm128<1><<<dim3(49, 16), dim3(256), 0, stream>>>(
            h2C, wT_ff1, ff_b1, ffiC, nullptr, mod, 2048, 512, 0);
        // FF2 + residual(x2) -> d_out
        gemm128<3><<<dim3(49, 4), dim3(256), 0, stream>>>(
            ffiC, wT_ff2, ff_b2, outp, outp, mod, 512, 2048, row0);
    }
}

// Round 5
// 1692.517 us; speedup vs baseline: 1.2416x; 1.0714x over previous
//
#include <hip/hip_runtime.h>
#include <cmath>

typedef unsigned short u16;
typedef unsigned short u16x2 __attribute__((ext_vector_type(2)));
typedef unsigned short u16x8 __attribute__((ext_vector_type(8)));
typedef short s16x8 __attribute__((ext_vector_type(8)));
typedef float f32x4 __attribute__((ext_vector_type(4)));
typedef float f32x2 __attribute__((ext_vector_type(2)));

#define B_SZ 16
#define HW 56
#define L_TOK 3136      // 56*56
#define C_DIM 512
#define NHEAD 16
#define DHEAD 32
#define WS7 7
#define NWIN 49
#define ROWS_TOTAL 50176   // 16*3136
#define MLP_DIM 2048
#define CHUNK_B 2
#define CHUNK_ROWS 6272    // CHUNK_B*3136
#define N_CHUNKS 8

__device__ __forceinline__ float bf2f(u16 u) {
    union { unsigned int i; float f; } z;
    z.i = ((unsigned int)u) << 16;
    return z.f;
}
__device__ __forceinline__ u16 f2bf(float f) {
    union { float f; unsigned int i; } z;
    z.f = f;
    unsigned int r = z.i + 0x7fffu + ((z.i >> 16) & 1u);
    return (u16)(r >> 16);
}

// async global->LDS, 16B per lane; LDS dest = wave-uniform base + lane*16
__device__ __forceinline__ void gl_lds16(const u16* g, u16* l) {
    __builtin_amdgcn_global_load_lds(
        (const __attribute__((address_space(1))) unsigned int*)g,
        (__attribute__((address_space(3))) unsigned int*)l,
        16, 0, 0);
}

// ---------------------------------------------------------------------------
// 1) mod = silu(emb) @ adaLN_w + adaLN_b -> fp32 [16,3072]
// ---------------------------------------------------------------------------
__global__ __launch_bounds__(256)
void mod_kernel(const float* __restrict__ emb, const float* __restrict__ w,
                const float* __restrict__ bias, float* __restrict__ mod)
{
    int b = blockIdx.y;
    int o = blockIdx.x * 256 + threadIdx.x;
    __shared__ float se[512];
    for (int i = threadIdx.x; i < 512; i += 256) {
        float e = emb[b * 512 + i];
        se[i] = e / (1.0f + expf(-e));
    }
    __syncthreads();
    float acc = bias[o];
    #pragma unroll 8
    for (int k = 0; k < 512; ++k)
        acc += se[k] * w[(size_t)k * 3072 + o];
    mod[b * 3072 + o] = acc;
}

// ---------------------------------------------------------------------------
// 2) weight transpose + bf16 cast: Wt[n][k] = bf16(W[k][n])
// ---------------------------------------------------------------------------
__global__ __launch_bounds__(1024)
void transpose_kernel(const float* __restrict__ W, u16* __restrict__ Wt, int K, int N)
{
    __shared__ float tile[32][33];
    int k0 = blockIdx.x * 32, n0 = blockIdx.y * 32;
    tile[threadIdx.y][threadIdx.x] = W[(size_t)(k0 + threadIdx.y) * N + (n0 + threadIdx.x)];
    __syncthreads();
    Wt[(size_t)(n0 + threadIdx.y) * K + (k0 + threadIdx.x)] = f2bf(tile[threadIdx.x][threadIdx.y]);
}

// ---------------------------------------------------------------------------
// 3) LN + adaLN modulate; wave-per-row (4 rows/block), no LDS / syncthreads.
//    fp32 in, bf16 out. Lane owns 8 channels (f32x4 x2 load, 16B bf16 store).
// ---------------------------------------------------------------------------
template<int WINDOWED>
__global__ __launch_bounds__(256)
void ln_kernel(const float* __restrict__ xin, const float* __restrict__ mod,
               u16* __restrict__ out, int shOff, int scOff, int rowBase)
{
    int wv   = threadIdx.x >> 6;
    int lane = threadIdx.x & 63;
    int rbl = blockIdx.x * 4 + wv;        // chunk-local row
    int rb  = rbl + rowBase;              // global sequence row
    int b = rb / L_TOK, l = rb - b * L_TOK;
    const float* xr = xin + (size_t)rb * C_DIM;
    int c0 = lane * 8;
    f32x4 u0 = *(const f32x4*)(xr + c0);
    f32x4 u1 = *(const f32x4*)(xr + c0 + 4);
    float s = u0.x + u0.y + u0.z + u0.w + u1.x + u1.y + u1.z + u1.w;
    float q = u0.x*u0.x + u0.y*u0.y + u0.z*u0.z + u0.w*u0.w
            + u1.x*u1.x + u1.y*u1.y + u1.z*u1.z + u1.w*u1.w;
    #pragma unroll
    for (int off = 32; off > 0; off >>= 1) {
        s += __shfl_xor(s, off);
        q += __shfl_xor(q, off);
    }
    float mu = s * (1.0f / 512.0f);
    float var = q * (1.0f / 512.0f) - mu * mu;
    float rstd = rsqrtf(var + 1e-6f);
    const float* mb = mod + b * 3072;
    f32x4 sc0 = *(const f32x4*)(mb + scOff + c0);
    f32x4 sc1 = *(const f32x4*)(mb + scOff + c0 + 4);
    f32x4 sh0 = *(const f32x4*)(mb + shOff + c0);
    f32x4 sh1 = *(const f32x4*)(mb + shOff + c0 + 4);
    float y[8];
    y[0] = (u0.x - mu) * rstd * (1.0f + sc0.x) + sh0.x;
    y[1] = (u0.y - mu) * rstd * (1.0f + sc0.y) + sh0.y;
    y[2] = (u0.z - mu) * rstd * (1.0f + sc0.z) + sh0.z;
    y[3] = (u0.w - mu) * rstd * (1.0f + sc0.w) + sh0.w;
    y[4] = (u1.x - mu) * rstd * (1.0f + sc1.x) + sh1.x;
    y[5] = (u1.y - mu) * rstd * (1.0f + sc1.y) + sh1.y;
    y[6] = (u1.z - mu) * rstd * (1.0f + sc1.z) + sh1.z;
    y[7] = (u1.w - mu) * rstd * (1.0f + sc1.w) + sh1.w;
    size_t drow;
    if (WINDOWED) {
        int hh = l / HW, ww = l - hh * HW;
        int hs = hh - 3; if (hs < 0) hs += HW;
        int ws2 = ww - 3; if (ws2 < 0) ws2 += HW;
        int wi = (hs / WS7) * 8 + (ws2 / WS7);
        int n  = (hs % WS7) * WS7 + (ws2 % WS7);
        int b_local = rbl / L_TOK;
        drow = (size_t)((b_local * 64 + wi) * NWIN + n);
    } else {
        drow = (size_t)rbl;
    }
    u16x8 o;
    #pragma unroll
    for (int i = 0; i < 8; ++i) o[i] = f2bf(y[i]);
    *(u16x8*)(out + drow * C_DIM + c0) = o;
}

// ---------------------------------------------------------------------------
// 4) GEMM: C[M,N] = A[M,K] @ Bt[N,K]^T + bias
//    128x128 tile, BK=32, 4 waves x (4x4) mfma_f32_16x16x32_bf16.
//    Staging via global_load_lds width=16 (m97 pattern).
// ---------------------------------------------------------------------------
template<int EPI>
__global__ __launch_bounds__(256)
void gemm128(const u16* __restrict__ A, const u16* __restrict__ Bt,
             const float* __restrict__ bias, void* __restrict__ outv,
             const float* __restrict__ resid, const float* __restrict__ mod,
             int N, int K, int rowOffset)
{
    __shared__ u16 sA[128][32];   // unpadded: global_load_lds is lane-contiguous
    __shared__ u16 sB[128][32];
    const int tid  = threadIdx.x;
    const int lane = tid & 63;
    const int wave = tid >> 6;
    const int wr = (wave >> 1) * 64;
    const int wc = (wave & 1) * 64;
    const int quad = lane >> 4;
    const int mrow = lane & 15;
    const int rowBase = blockIdx.x * 128;
    const int colBase = blockIdx.y * 128;

    const int r0   = wave * 32;
    const int lrow = lane >> 2;
    const int lcol = (lane & 3) * 8;          // u16 offset in row
    const u16* gA = A  + (size_t)(rowBase + r0 + lrow) * K + lcol;
    const u16* gB = Bt + (size_t)(colBase + r0 + lrow) * K + lcol;
    u16* lA0 = &sA[r0][0];
    u16* lA1 = &sA[r0 + 16][0];
    u16* lB0 = &sB[r0][0];
    u16* lB1 = &sB[r0 + 16][0];
    const size_t gstep = (size_t)16 * K;

    f32x4 acc[4][4] = {};

    for (int kk = 0; kk < K; kk += 32) {
        __syncthreads();
        gl_lds16(gA + kk,         lA0);
        gl_lds16(gA + kk + gstep, lA1);
        gl_lds16(gB + kk,         lB0);
        gl_lds16(gB + kk + gstep, lB1);
        __syncthreads();
        s16x8 af[4], bg[4];
        #pragma unroll
        for (int tt = 0; tt < 4; ++tt) {
            af[tt] = *(const s16x8*)&sA[wr + tt * 16 + mrow][quad * 8];
            bg[tt] = *(const s16x8*)&sB[wc + tt * 16 + mrow][quad * 8];
        }
        #pragma unroll
        for (int tm = 0; tm < 4; ++tm)
            #pragma unroll
            for (int tn = 0; tn < 4; ++tn)
                acc[tm][tn] = __builtin_amdgcn_mfma_f32_16x16x32_bf16(
                    af[tm], bg[tn], acc[tm][tn], 0, 0, 0);
    }

    #pragma unroll
    for (int tm = 0; tm < 4; ++tm) {
        #pragma unroll
        for (int tn = 0; tn < 4; ++tn) {
            int col = colBase + wc + tn * 16 + mrow;
            float bv = bias[col];
            #pragma unroll
            for (int i = 0; i < 4; ++i) {
                int r = rowBase + wr + tm * 16 + quad * 4 + i;   // chunk-local
                float v = acc[tm][tn][i] + bv;
                if constexpr (EPI == 0) {
                    ((u16*)outv)[(size_t)r * N + col] = f2bf(v);
                } else if constexpr (EPI == 1) {
                    float g = 0.5f * v * (1.0f + erff(v * 0.70710678118654752f));
                    ((u16*)outv)[(size_t)r * N + col] = f2bf(g);
                } else if constexpr (EPI == 2) {
                    int rg = r + rowOffset;        // global window-layout row
                    int b = rg / L_TOK;
                    int rem = rg - b * L_TOK;
                    int wi = rem / NWIN;
                    int n  = rem - wi * NWIN;
                    int hs  = (wi >> 3) * WS7 + n / WS7;
                    int ws2 = (wi & 7) * WS7 + n % WS7;
                    int hh = hs + 3;  if (hh >= HW)  hh -= HW;
                    int ww = ws2 + 3; if (ww >= HW)  ww -= HW;
                    size_t dst = ((size_t)(b * L_TOK + hh * HW + ww)) * C_DIM + col;
                    float g = mod[b * 3072 + 1024 + col];
                    ((float*)outv)[dst] = resid[dst] + g * v;
                } else {  // EPI == 3
                    int rg = r + rowOffset;        // global sequence row
                    int b = rg / L_TOK;
                    size_t dst = (size_t)rg * C_DIM + col;
                    float g = mod[b * 3072 + 2560 + col];
                    ((float*)outv)[dst] = resid[dst] + g * v;
                }
            }
        }
    }
}

// ---------------------------------------------------------------------------
// 5) windowed attention, one block per (chunk-local window, head).
//    K stored TRANSPOSED in LDS (skT[d][m], rows padded to 52): QK^T reads
//    are lane-stride-1 (was 32-way bank conflict on sk[m][d] = 1.79e7
//    conflict-cycles/dispatch).
// ---------------------------------------------------------------------------
__global__ __launch_bounds__(256)
void attn_kernel(const u16* __restrict__ qkv, const float* __restrict__ bias_table,
                 u16* __restrict__ out)
{
    int w = blockIdx.x;       // chunk-local: b_local*64 + wi
    int h = blockIdx.y;       // 0..15
    int wi = w & 63;
    __shared__ float sq[NWIN][DHEAD];       // broadcast reads
    __shared__ float skT[DHEAD][NWIN + 3];  // 32x52, stride-1 reads
    __shared__ float sv[NWIN][DHEAD];       // stride-1 reads
    __shared__ float sS[NWIN][NWIN + 1];
    int t = threadIdx.x;
    const float scale = 0.17677669529663687f;   // 1/sqrt(32)

    for (int e = t; e < NWIN * DHEAD; e += 256) {
        int n = e >> 5, d = e & 31;
        size_t base = ((size_t)(w * NWIN + n)) * 1536 + h * DHEAD + d;
        sq[n][d]  = bf2f(qkv[base]) * scale;
        skT[d][n] = bf2f(qkv[base + 512]);
        sv[n][d]  = bf2f(qkv[base + 1024]);
    }
    __syncthreads();

    int wh = wi >> 3, ww = wi & 7;
    for (int e = t; e < NWIN * NWIN; e += 256) {
        int n = e / NWIN, m = e - n * NWIN;
        float s = 0.0f;
        #pragma unroll
        for (int d = 0; d < DHEAD; ++d) s += sq[n][d] * skT[d][m];
        int nh_ = n / WS7, nw_ = n % WS7;
        int mh_ = m / WS7, mw_ = m % WS7;
        int idx = (nh_ - mh_ + 6) * 13 + (nw_ - mw_ + 6);
        s += bias_table[idx * NHEAD + h];
        // shift-mask regions on the shifted grid; bands at 49 and 53
        int gnh = wh * WS7 + nh_, gnw = ww * WS7 + nw_;
        int gmh = wh * WS7 + mh_, gmw = ww * WS7 + mw_;
        int rn = (gnh < 49 ? 0 : (gnh < 53 ? 1 : 2)) * 3 + (gnw < 49 ? 0 : (gnw < 53 ? 1 : 2));
        int rm = (gmh < 49 ? 0 : (gmh < 53 ? 1 : 2)) * 3 + (gmw < 49 ? 0 : (gmw < 53 ? 1 : 2));
        if (rn != rm) s -= 100.0f;
        sS[n][m] = s;
    }
    __syncthreads();

    if (t < NWIN) {
        float mx = -1e30f;
        for (int m = 0; m < NWIN; ++m) mx = fmaxf(mx, sS[t][m]);
        float sum = 0.0f;
        for (int m = 0; m < NWIN; ++m) { float p = expf(sS[t][m] - mx); sS[t][m] = p; sum += p; }
        float inv = 1.0f / sum;
        for (int m = 0; m < NWIN; ++m) sS[t][m] *= inv;
    }
    __syncthreads();

    for (int e = t; e < NWIN * DHEAD; e += 256) {
        int n = e >> 5, d = e & 31;
        float o = 0.0f;
        #pragma unroll 7
        for (int m = 0; m < NWIN; ++m) o += sS[n][m] * sv[m][d];
        out[((size_t)(w * NWIN + n)) * C_DIM + h * DHEAD + d] = f2bf(o);
    }
}

// ---------------------------------------------------------------------------
// fp32 I/O, bf16 compute core. x2 lives in d_out. Workspace peak 70.7 MB.
// ---------------------------------------------------------------------------
extern "C" void kernel_launch(void* const* d_in, const int* in_sizes, int n_in,
                              void* d_out, int out_size, void* d_ws, size_t ws_size,
                              hipStream_t stream)
{
    const float* x       = (const float*)d_in[0];
    const float* emb     = (const float*)d_in[1];
    const float* adaLN_w = (const float*)d_in[2];
    const float* adaLN_b = (const float*)d_in[3];
    const float* qkv_w   = (const float*)d_in[4];
    const float* qkv_b   = (const float*)d_in[5];
    const float* proj_w  = (const float*)d_in[6];
    const float* proj_b  = (const float*)d_in[7];
    const float* relb    = (const float*)d_in[8];
    const float* ff_w1   = (const float*)d_in[9];
    const float* ff_b1   = (const float*)d_in[10];
    const float* ff_w2   = (const float*)d_in[11];
    const float* ff_b2   = (const float*)d_in[12];
    float* outp = (float*)d_out;

    char* ws = (char*)d_ws;
    float* mod   = (float*)(ws + 0);                  //    196,608 B
    u16* wT_qkv  = (u16*)(ws + 196608);               //  1,572,864 B
    u16* wT_proj = (u16*)(ws + 1769472);              //    524,288 B
    u16* wT_ff1  = (u16*)(ws + 2293760);              //  2,097,152 B
    u16* wT_ff2  = (u16*)(ws + 4390912);              //  2,097,152 B
    u16* winC    = (u16*)(ws + 6488064);              //  6,422,528 B [6272,512]
    u16* aoC     = (u16*)(ws + 12910592);             //  6,422,528 B [6272,512]
    u16* h2C     = (u16*)(ws + 19333120);             //  6,422,528 B [6272,512]
    u16* qkvC    = (u16*)(ws + 25755648);             // 19,267,584 B [6272,1536]
    u16* ffiC    = (u16*)(ws + 45023232);             // 25,690,112 B [6272,2048]
    // total: 70,713,344 B

    // prolog (once)
    mod_kernel<<<dim3(12, 16), dim3(256), 0, stream>>>(emb, adaLN_w, adaLN_b, mod);
    transpose_kernel<<<dim3(16, 48), dim3(32, 32), 0, stream>>>(qkv_w,  wT_qkv, 512, 1536);
    transpose_kernel<<<dim3(16, 16), dim3(32, 32), 0, stream>>>(proj_w, wT_proj, 512, 512);
    transpose_kernel<<<dim3(16, 64), dim3(32, 32), 0, stream>>>(ff_w1,  wT_ff1, 512, 2048);
    transpose_kernel<<<dim3(64, 16), dim3(32, 32), 0, stream>>>(ff_w2,  wT_ff2, 2048, 512);

    for (int c = 0; c < N_CHUNKS; ++c) {
        int row0 = c * CHUNK_ROWS;
        // LN1 + modulate + shift + window partition: x[row0..] -> winC
        ln_kernel<1><<<dim3(CHUNK_ROWS / 4), dim3(256), 0, stream>>>(
            x, mod, winC, 0, 512, row0);
        // qkv GEMM: winC [6272,512] @ wT_qkv -> qkvC [6272,1536]
        gemm128<0><<<dim3(49, 12), dim3(256), 0, stream>>>(
            winC, wT_qkv, qkv_b, qkvC, nullptr, mod, 1536, 512, 0);
        // attention -> aoC
        attn_kernel<<<dim3(CHUNK_B * 64, 16), dim3(256), 0, stream>>>(qkvC, relb, aoC);
        // proj + window reverse + unshift + residual(x) -> d_out (x2, fp32)
        gemm128<2><<<dim3(49, 4), dim3(256), 0, stream>>>(
            aoC, wT_proj, proj_b, outp, x, mod, 512, 512, row0);
        // LN2 + modulate: d_out[row0..] -> h2C (bf16)
        ln_kernel<0><<<dim3(CHUNK_ROWS / 4), dim3(256), 0, stream>>>(
            outp, mod, h2C, 1536, 2048, row0);
        // FF1 + GELU: h2C -> ffiC
        gemm128<1><<<dim3(49, 16), dim3(256), 0, stream>>>(
            h2C, wT_ff1, ff_b1, ffiC, nullptr, mod, 2048, 512, 0);
        // FF2 + residual(x2) -> d_out
        gemm128<3><<<dim3(49, 4), dim3(256), 0, stream>>>(
            ffiC, wT_ff2, ff_b2, outp, outp, mod, 512, 2048, row0);
    }
}